// Round 12
// baseline (450.560 us; speedup 1.0000x reference)
//
#include <hip/hip_runtime.h>
#include <math.h>
#include <stdint.h>
#include <stddef.h>

#define N_NODES 8192
#define N_EDGES 524288
#define N_PAIRS 262144
#define N_TYPES 86
#define F1 128
#define F2 64

typedef unsigned short ushort_t;
typedef unsigned int uint_t;
typedef __attribute__((ext_vector_type(8))) short bfrag;
typedef __attribute__((ext_vector_type(4))) uint_t ufrag;
typedef __attribute__((ext_vector_type(4))) float ffrag;

__device__ inline ushort_t f2bf(float f) {
  uint_t u = __float_as_uint(f);
  uint_t r = u + 0x7fffu + ((u >> 16) & 1u);
  return (ushort_t)(r >> 16);
}
__device__ inline float bf2f(ushort_t h) {
  return __uint_as_float(((uint_t)h) << 16);
}

// split 8 fp32 (ascending k) into hi/lo bf16 packed frags.
// v_cvt_pk_bf16_f32: D = [bf16(S1) | bf16(S0)] (RNE). lo-part residual is
// fp32-exact (Sterbenz), then RNE to bf16 -> 2^-17 rel total.
__device__ __forceinline__ void cvt8(float4 v0, float4 v1, ufrag& h, ufrag& l) {
  uint_t h0, h1, h2, h3, l0, l1, l2, l3;
  asm("v_cvt_pk_bf16_f32 %0, %1, %2" : "=v"(h0) : "v"(v0.x), "v"(v0.y));
  asm("v_cvt_pk_bf16_f32 %0, %1, %2" : "=v"(h1) : "v"(v0.z), "v"(v0.w));
  asm("v_cvt_pk_bf16_f32 %0, %1, %2" : "=v"(h2) : "v"(v1.x), "v"(v1.y));
  asm("v_cvt_pk_bf16_f32 %0, %1, %2" : "=v"(h3) : "v"(v1.z), "v"(v1.w));
  float e0 = v0.x - __uint_as_float(h0 << 16);
  float e1 = v0.y - __uint_as_float(h0 & 0xffff0000u);
  float e2 = v0.z - __uint_as_float(h1 << 16);
  float e3 = v0.w - __uint_as_float(h1 & 0xffff0000u);
  float e4 = v1.x - __uint_as_float(h2 << 16);
  float e5 = v1.y - __uint_as_float(h2 & 0xffff0000u);
  float e6 = v1.z - __uint_as_float(h3 << 16);
  float e7 = v1.w - __uint_as_float(h3 & 0xffff0000u);
  asm("v_cvt_pk_bf16_f32 %0, %1, %2" : "=v"(l0) : "v"(e0), "v"(e1));
  asm("v_cvt_pk_bf16_f32 %0, %1, %2" : "=v"(l1) : "v"(e2), "v"(e3));
  asm("v_cvt_pk_bf16_f32 %0, %1, %2" : "=v"(l2) : "v"(e4), "v"(e5));
  asm("v_cvt_pk_bf16_f32 %0, %1, %2" : "=v"(l3) : "v"(e6), "v"(e7));
  h.x = h0; h.y = h1; h.z = h2; h.w = h3;
  l.x = l0; l.y = l1; l.z = l2; l.w = l3;
}

// ---------------- degree / CSR build ----------------

__global__ void zero_k(int* __restrict__ p) {
  p[blockIdx.x * 256 + threadIdx.x] = 0;
}

__global__ void count_deg_k(const int* __restrict__ dst, int* __restrict__ cnt) {
  int e = blockIdx.x * blockDim.x + threadIdx.x;
  if (e < N_EDGES) atomicAdd(&cnt[dst[e]], 1);
}

// scan + dinv fused
__global__ void scan_k(const int* __restrict__ cnt, int* __restrict__ rp,
                       int* __restrict__ fill, float* __restrict__ dinv) {
  __shared__ int s[1024];
  int t = threadIdx.x;
  int v[8];
  int sum = 0;
#pragma unroll
  for (int i = 0; i < 8; i++) {
    v[i] = cnt[t * 8 + i];
    dinv[t * 8 + i] = 1.0f / sqrtf((float)(v[i] + 1));  // +1 self-loop
    sum += v[i];
  }
  s[t] = sum;
  __syncthreads();
  for (int off = 1; off < 1024; off <<= 1) {
    int add = (t >= off) ? s[t - off] : 0;
    __syncthreads();
    s[t] += add;
    __syncthreads();
  }
  int excl = s[t] - sum;
#pragma unroll
  for (int i = 0; i < 8; i++) {
    rp[t * 8 + i] = excl;
    fill[t * 8 + i] = excl;
    excl += v[i];
  }
  if (t == 1023) rp[N_NODES] = excl;
}

__global__ void scatter_k(const int* __restrict__ src, const int* __restrict__ dst,
                          int* fill, int* __restrict__ csr) {
  int e = blockIdx.x * blockDim.x + threadIdx.x;
  if (e < N_EDGES) {
    int d = dst[e];
    int pos = atomicAdd(&fill[d], 1);
    csr[pos] = src[e];
  }
}

// ---------------- W1 split + transpose: W1th/W1tl[n][k] = hi/lo(W1[k][n]) ----------------

__global__ __launch_bounds__(256) void w1split_k(const float* __restrict__ W1,
                                                 ushort_t* __restrict__ W1th,
                                                 ushort_t* __restrict__ W1tl) {
  __shared__ ushort_t lh[32 * 65];
  __shared__ ushort_t ll[32 * 65];
  int tid = threadIdx.x;
  int k0 = blockIdx.x * 64;
  int n0 = blockIdx.y * 32;
#pragma unroll
  for (int i = 0; i < 8; i++) {
    int c = tid + 256 * i;
    int kr = c >> 5, nc = c & 31;
    float v = W1[(size_t)(k0 + kr) * F1 + n0 + nc];
    ushort_t h = f2bf(v);
    ushort_t l = f2bf(v - bf2f(h));
    lh[nc * 65 + kr] = h;
    ll[nc * 65 + kr] = l;
  }
  __syncthreads();
#pragma unroll
  for (int i = 0; i < 2; i++) {
    int c = tid + 256 * i;
    int buf = c >> 8;
    int cc = c & 255;
    int nr = cc >> 3, kc = cc & 7;
    const ushort_t* l = buf ? ll : lh;
    uint4 u;
    u.x = (uint_t)l[nr * 65 + kc * 8 + 0] | ((uint_t)l[nr * 65 + kc * 8 + 1] << 16);
    u.y = (uint_t)l[nr * 65 + kc * 8 + 2] | ((uint_t)l[nr * 65 + kc * 8 + 3] << 16);
    u.z = (uint_t)l[nr * 65 + kc * 8 + 4] | ((uint_t)l[nr * 65 + kc * 8 + 5] << 16);
    u.w = (uint_t)l[nr * 65 + kc * 8 + 6] | ((uint_t)l[nr * 65 + kc * 8 + 7] << 16);
    ushort_t* dst = (buf ? W1tl : W1th) + (size_t)(n0 + nr) * N_NODES + k0 + kc * 8;
    *(uint4*)dst = u;
  }
}

// ---------------- GEMM1: zero-LDS zero-barrier register dataflow ----------------
// 256 thr (4 waves), block = M32 x K1024 (grid 8 x 256 = 2048 blocks).
// Per lane: A frag loaded DIRECTLY from x at [row=m_blk+mi*16+lrow][k0+kgrp*8]
// (16B; consecutive steps walk each row's 128B lines sequentially -> L1-friendly),
// converted in-reg to split bf16 (cvt8). B frags (hi+lo) loaded per-lane from
// L2-resident W1t. 12 MFMA/step/wave. NO LDS, NO barriers, NO waitcnt asm:
// pure TLP/ILP streaming (the regime where this box measures ~7 TB/s).

__global__ __launch_bounds__(256, 4) void gemm1_df_k(const float* __restrict__ x,
                                                     const ushort_t* __restrict__ W1th,
                                                     const ushort_t* __restrict__ W1tl,
                                                     float* __restrict__ part, int kspan) {
  int tid = threadIdx.x;
  int wave = tid >> 6, lane = tid & 63;
  int lrow = lane & 15, kgrp = lane >> 4;
  int m_blk = blockIdx.y * 32;
  int kbase = blockIdx.x * kspan;
  int steps = kspan >> 5;  // k32 per step

  const float* pa0 = x + (size_t)(m_blk + lrow) * N_NODES + kbase + kgrp * 8;
  const float* pa1 = pa0 + (size_t)16 * N_NODES;
  size_t bo0 = (size_t)(wave * 32 + lrow) * N_NODES + kbase + kgrp * 8;
  size_t bo1 = bo0 + (size_t)16 * N_NODES;
  const ushort_t* pbh0 = W1th + bo0;
  const ushort_t* pbh1 = W1th + bo1;
  const ushort_t* pbl0 = W1tl + bo0;
  const ushort_t* pbl1 = W1tl + bo1;

  ffrag acc[2][2];
#pragma unroll
  for (int mi = 0; mi < 2; mi++)
#pragma unroll
    for (int ni = 0; ni < 2; ni++) acc[mi][ni] = (ffrag)(0.0f);

  // prefetch A step 0
  float4 a00 = *(const float4*)pa0;
  float4 a01 = *(const float4*)(pa0 + 4);
  float4 a10 = *(const float4*)pa1;
  float4 a11 = *(const float4*)(pa1 + 4);
  pa0 += 32; pa1 += 32;

#define STEP_BODY(PREFETCH)                                                     \
  {                                                                             \
    bfrag bh0 = *(const bfrag*)pbh0;                                            \
    bfrag bh1 = *(const bfrag*)pbh1;                                            \
    bfrag bl0 = *(const bfrag*)pbl0;                                            \
    bfrag bl1 = *(const bfrag*)pbl1;                                            \
    pbh0 += 32; pbh1 += 32; pbl0 += 32; pbl1 += 32;                             \
    float4 n00, n01, n10, n11;                                                  \
    if (PREFETCH) {                                                             \
      n00 = *(const float4*)pa0;                                                \
      n01 = *(const float4*)(pa0 + 4);                                          \
      n10 = *(const float4*)pa1;                                                \
      n11 = *(const float4*)(pa1 + 4);                                          \
      pa0 += 32; pa1 += 32;                                                     \
    }                                                                           \
    ufrag h0, l0, h1, l1;                                                       \
    cvt8(a00, a01, h0, l0);                                                     \
    cvt8(a10, a11, h1, l1);                                                     \
    bfrag ah0 = __builtin_bit_cast(bfrag, h0);                                  \
    bfrag al0 = __builtin_bit_cast(bfrag, l0);                                  \
    bfrag ah1 = __builtin_bit_cast(bfrag, h1);                                  \
    bfrag al1 = __builtin_bit_cast(bfrag, l1);                                  \
    acc[0][0] = __builtin_amdgcn_mfma_f32_16x16x32_bf16(ah0, bh0, acc[0][0], 0, 0, 0); \
    acc[0][1] = __builtin_amdgcn_mfma_f32_16x16x32_bf16(ah0, bh1, acc[0][1], 0, 0, 0); \
    acc[1][0] = __builtin_amdgcn_mfma_f32_16x16x32_bf16(ah1, bh0, acc[1][0], 0, 0, 0); \
    acc[1][1] = __builtin_amdgcn_mfma_f32_16x16x32_bf16(ah1, bh1, acc[1][1], 0, 0, 0); \
    acc[0][0] = __builtin_amdgcn_mfma_f32_16x16x32_bf16(ah0, bl0, acc[0][0], 0, 0, 0); \
    acc[0][1] = __builtin_amdgcn_mfma_f32_16x16x32_bf16(ah0, bl1, acc[0][1], 0, 0, 0); \
    acc[1][0] = __builtin_amdgcn_mfma_f32_16x16x32_bf16(ah1, bl0, acc[1][0], 0, 0, 0); \
    acc[1][1] = __builtin_amdgcn_mfma_f32_16x16x32_bf16(ah1, bl1, acc[1][1], 0, 0, 0); \
    acc[0][0] = __builtin_amdgcn_mfma_f32_16x16x32_bf16(al0, bh0, acc[0][0], 0, 0, 0); \
    acc[0][1] = __builtin_amdgcn_mfma_f32_16x16x32_bf16(al0, bh1, acc[0][1], 0, 0, 0); \
    acc[1][0] = __builtin_amdgcn_mfma_f32_16x16x32_bf16(al1, bh0, acc[1][0], 0, 0, 0); \
    acc[1][1] = __builtin_amdgcn_mfma_f32_16x16x32_bf16(al1, bh1, acc[1][1], 0, 0, 0); \
    if (PREFETCH) { a00 = n00; a01 = n01; a10 = n10; a11 = n11; }               \
  }

#pragma unroll 2
  for (int s = 0; s < steps - 1; ++s) STEP_BODY(1)
  STEP_BODY(0)
#undef STEP_BODY

  // epilogue: C[row=(lane>>4)*4+r][col=lane&15] per 16x16 frag
  float* outp = part + (size_t)blockIdx.x * (N_NODES * F1);
#pragma unroll
  for (int mi = 0; mi < 2; mi++) {
#pragma unroll
    for (int ni = 0; ni < 2; ni++) {
      int col = wave * 32 + ni * 16 + lrow;
#pragma unroll
      for (int r = 0; r < 4; r++) {
        int row = m_blk + mi * 16 + kgrp * 4 + r;
        outp[(size_t)row * F1 + col] = acc[mi][ni][r];
      }
    }
  }
}

// in-place safe: each thread reads all S parts at its index, then writes part[0].
__global__ void reduceS_k(const float* __restrict__ part, float* __restrict__ xw1, int S) {
  int i = blockIdx.x * blockDim.x + threadIdx.x;
  float4 a = ((const float4*)part)[i];
  for (int s = 1; s < S; s++) {
    float4 b = ((const float4*)(part + (size_t)s * N_NODES * F1))[i];
    a.x += b.x; a.y += b.y; a.z += b.z; a.w += b.w;
  }
  ((float4*)xw1)[i] = a;
}

// ---------------- aggregation (gather over CSR) + bias + relu ----------------

template <int F>
__global__ void agg_k(const float* __restrict__ xw, const int* __restrict__ csr,
                      const int* __restrict__ rp, const float* __restrict__ dinv,
                      const float* __restrict__ bias, float* __restrict__ hout) {
  int node = blockIdx.x;
  int f = threadIdx.x;  // F threads
  __shared__ int sidx[F];
  __shared__ float sdv[F];
  int beg = rp[node], end = rp[node + 1];
  float acc = 0.f;
  for (int base = beg; base < end; base += F) {
    int n = end - base;
    if (n > F) n = F;
    __syncthreads();
    if (f < n) {
      int s = csr[base + f];
      sidx[f] = s;
      sdv[f] = dinv[s];
    }
    __syncthreads();
    for (int i = 0; i < n; i++) acc += xw[(size_t)sidx[i] * F + f] * sdv[i];
  }
  float dv = dinv[node];
  float v = (acc + xw[(size_t)node * F + f] * dv) * dv + bias[f];
  hout[(size_t)node * F + f] = v > 0.f ? v : 0.f;
}

// ---------------- GEMM2: h1[8192,128] @ W2[128,64] ----------------

__global__ __launch_bounds__(256) void gemm2_k(const float* __restrict__ h1,
                                               const float* __restrict__ W2,
                                               float* __restrict__ xw2) {
  __shared__ float W2s[F1 * F2];
  __shared__ float As[16 * F1];
  int tid = threadIdx.x;
  int r0 = blockIdx.x * 16;
#pragma unroll
  for (int j = 0; j < 8; j++)
    ((float4*)W2s)[tid + 256 * j] = ((const float4*)W2)[tid + 256 * j];
#pragma unroll
  for (int j = 0; j < 2; j++)
    ((float4*)As)[tid + 256 * j] = ((const float4*)(h1 + (size_t)r0 * F1))[tid + 256 * j];
  __syncthreads();
  int r = tid >> 4, c4 = tid & 15;
  float4 acc = make_float4(0.f, 0.f, 0.f, 0.f);
#pragma unroll 8
  for (int k = 0; k < F1; k++) {
    float a = As[r * F1 + k];
    float4 bv = *(float4*)&W2s[k * F2 + 4 * c4];
    acc.x += a * bv.x; acc.y += a * bv.y; acc.z += a * bv.z; acc.w += a * bv.w;
  }
  *(float4*)&xw2[(size_t)(r0 + r) * F2 + 4 * c4] = acc;
}

// ---------------- P tables: P[i][0:86]=h2[i]@Wfc[:64], P[i][86:172]=h2[i]@Wfc[64:] ----------------

__global__ void pboth_k(const float* __restrict__ h2, const float* __restrict__ Wfc,
                        float* __restrict__ P) {
  __shared__ float hs[64 * 16];
  int tid = threadIdx.x;  // 192
  int r0 = blockIdx.x * 16;
  for (int idx = tid; idx < 256; idx += 192) {
    int row = idx >> 4, k4 = idx & 15;
    float4 h = *(const float4*)&h2[(size_t)(r0 + row) * F2 + 4 * k4];
    hs[(4 * k4 + 0) * 16 + row] = h.x;
    hs[(4 * k4 + 1) * 16 + row] = h.y;
    hs[(4 * k4 + 2) * 16 + row] = h.z;
    hs[(4 * k4 + 3) * 16 + row] = h.w;
  }
  __syncthreads();
  if (tid < 172) {
    int half = tid < 86 ? 0 : 1;
    int j = tid - 86 * half;
    const float* wp = Wfc + (size_t)(64 * half) * N_TYPES + j;
    float acc[16];
#pragma unroll
    for (int r = 0; r < 16; r++) acc[r] = 0.f;
    for (int k = 0; k < 64; k++) {
      float w = wp[(size_t)k * N_TYPES];
      const float* hk = &hs[k * 16];
#pragma unroll
      for (int r = 0; r < 16; r++) acc[r] += hk[r] * w;
    }
#pragma unroll
    for (int r = 0; r < 16; r++) P[(size_t)(r0 + r) * 172 + tid] = acc[r];
  }
}

// ---------------- final: out[p][t] = sigmoid(P1[d1[p]][t] + P2[d2[p]][t] + bfc[t]) ----------------

__global__ void final_k(const float* __restrict__ P, const int* __restrict__ d1,
                        const int* __restrict__ d2, const float* __restrict__ bfc,
                        float* __restrict__ out) {
  int gid = blockIdx.x * blockDim.x + threadIdx.x;
  if (gid >= N_PAIRS * 43) return;
  int p = gid / 43;
  int j = gid - p * 43;
  int a = d1[p], b = d2[p];
  float2 v1 = *(const float2*)&P[(size_t)a * 172 + 2 * j];
  float2 v2 = *(const float2*)&P[(size_t)b * 172 + 86 + 2 * j];
  float2 bb = *(const float2*)&bfc[2 * j];
  float z0 = v1.x + v2.x + bb.x;
  float z1 = v1.y + v2.y + bb.y;
  float2 o;
  o.x = 1.0f / (1.0f + expf(-z0));
  o.y = 1.0f / (1.0f + expf(-z1));
  *(float2*)&out[(size_t)p * 86 + 2 * j] = o;
}

// ---------------- launch ----------------

extern "C" void kernel_launch(void* const* d_in, const int* in_sizes, int n_in,
                              void* d_out, int out_size, void* d_ws, size_t ws_size,
                              hipStream_t stream) {
  const float* x   = (const float*)d_in[0];
  const int*   ei  = (const int*)d_in[1];
  const int*   d1  = (const int*)d_in[2];
  const int*   d2  = (const int*)d_in[3];
  const float* W1  = (const float*)d_in[4];
  const float* b1  = (const float*)d_in[5];
  const float* W2  = (const float*)d_in[6];
  const float* b2  = (const float*)d_in[7];
  const float* Wfc = (const float*)d_in[8];
  const float* bfc = (const float*)d_in[9];
  float* out = (float*)d_out;

  const int* esrc = ei;
  const int* edst = ei + N_EDGES;

  char* w = (char*)d_ws;
  size_t off = 0;
  auto alloc = [&](size_t bytes) -> char* {
    char* p = w + off;
    off += (bytes + 255) & ~(size_t)255;
    return p;
  };
  int*      cnt  = (int*)alloc((size_t)N_NODES * 4);
  float*    dinv = (float*)alloc((size_t)N_NODES * 4);
  int*      rp   = (int*)alloc((size_t)(N_NODES + 1) * 4);
  int*      fill = (int*)alloc((size_t)N_NODES * 4);
  int*      csr  = (int*)alloc((size_t)N_EDGES * 4);
  ushort_t* W1th = (ushort_t*)alloc((size_t)N_NODES * F1 * 2);
  ushort_t* W1tl = (ushort_t*)alloc((size_t)N_NODES * F1 * 2);
  float*    h1   = (float*)alloc((size_t)N_NODES * F1 * 4);
  float*    xw2  = (float*)alloc((size_t)N_NODES * F2 * 4);
  float*    h2   = (float*)alloc((size_t)N_NODES * F2 * 4);
  float*    P    = (float*)alloc((size_t)N_NODES * 172 * 4);

  size_t partBytes = (size_t)N_NODES * F1 * 4;  // 4MB per split
  int S = 8;
  while (S > 1 && off + (size_t)S * partBytes > ws_size) S >>= 1;
  float* part = (float*)alloc((size_t)S * partBytes);
  float* xw1 = part;  // alias; reduceS_k is index-aligned in-place safe
  if (off > ws_size) return;

  zero_k<<<N_NODES / 256, 256, 0, stream>>>(cnt);
  count_deg_k<<<N_EDGES / 256, 256, 0, stream>>>(edst, cnt);
  scan_k<<<1, 1024, 0, stream>>>(cnt, rp, fill, dinv);
  scatter_k<<<N_EDGES / 256, 256, 0, stream>>>(esrc, edst, fill, csr);

  w1split_k<<<dim3(N_NODES / 64, F1 / 32), 256, 0, stream>>>(W1, W1th, W1tl);
  // grid (S, M-blocks): wgid%S == K-slice -> per-XCD B-slice L2 locality
  gemm1_df_k<<<dim3(S, N_NODES / 32), 256, 0, stream>>>(x, W1th, W1tl, part, N_NODES / S);
  if (S > 1)
    reduceS_k<<<(N_NODES * F1 / 4) / 256, 256, 0, stream>>>(part, xw1, S);
  agg_k<F1><<<N_NODES, F1, 0, stream>>>(xw1, csr, rp, dinv, b1, h1);

  gemm2_k<<<N_NODES / 16, 256, 0, stream>>>(h1, W2, xw2);
  agg_k<F2><<<N_NODES, F2, 0, stream>>>(xw2, csr, rp, dinv, b2, h2);

  pboth_k<<<N_NODES / 16, 192, 0, stream>>>(h2, Wfc, P);
  final_k<<<(N_PAIRS * 43 + 255) / 256, 256, 0, stream>>>(P, d1, d2, bfc, out);
}

// Round 13
// 265.376 us; speedup vs baseline: 1.6978x; 1.6978x over previous
//
#include <hip/hip_runtime.h>
#include <math.h>
#include <stdint.h>
#include <stddef.h>

#define N_NODES 8192
#define N_EDGES 524288
#define N_PAIRS 262144
#define N_TYPES 86
#define F1 128
#define F2 64

typedef unsigned short ushort_t;
typedef unsigned int uint_t;
typedef __attribute__((ext_vector_type(8))) short bfrag;
typedef __attribute__((ext_vector_type(4))) float ffrag;

typedef __attribute__((address_space(3))) char lds_char;
typedef __attribute__((address_space(1))) const char g_char;

__device__ __forceinline__ void gload16(const void* g, void* l) {
  // 16B global -> LDS direct (dest = wave-uniform base + lane*16)
  __builtin_amdgcn_global_load_lds((const g_char*)g, (lds_char*)l, 16, 0, 0);
}

__device__ inline ushort_t f2bf(float f) {
  uint_t u = __float_as_uint(f);
  uint_t r = u + 0x7fffu + ((u >> 16) & 1u);
  return (ushort_t)(r >> 16);
}
__device__ inline float bf2f(ushort_t h) {
  return __uint_as_float(((uint_t)h) << 16);
}

// ---------------- degree / CSR build ----------------

__global__ void zero_k(int* __restrict__ p) {
  p[blockIdx.x * 256 + threadIdx.x] = 0;
}

__global__ void count_deg_k(const int* __restrict__ dst, int* __restrict__ cnt) {
  int e = blockIdx.x * blockDim.x + threadIdx.x;
  if (e < N_EDGES) atomicAdd(&cnt[dst[e]], 1);
}

// scan + dinv fused
__global__ void scan_k(const int* __restrict__ cnt, int* __restrict__ rp,
                       int* __restrict__ fill, float* __restrict__ dinv) {
  __shared__ int s[1024];
  int t = threadIdx.x;
  int v[8];
  int sum = 0;
#pragma unroll
  for (int i = 0; i < 8; i++) {
    v[i] = cnt[t * 8 + i];
    dinv[t * 8 + i] = 1.0f / sqrtf((float)(v[i] + 1));  // +1 self-loop
    sum += v[i];
  }
  s[t] = sum;
  __syncthreads();
  for (int off = 1; off < 1024; off <<= 1) {
    int add = (t >= off) ? s[t - off] : 0;
    __syncthreads();
    s[t] += add;
    __syncthreads();
  }
  int excl = s[t] - sum;
#pragma unroll
  for (int i = 0; i < 8; i++) {
    rp[t * 8 + i] = excl;
    fill[t * 8 + i] = excl;
    excl += v[i];
  }
  if (t == 1023) rp[N_NODES] = excl;
}

__global__ void scatter_k(const int* __restrict__ src, const int* __restrict__ dst,
                          int* fill, int* __restrict__ csr) {
  int e = blockIdx.x * blockDim.x + threadIdx.x;
  if (e < N_EDGES) {
    int d = dst[e];
    int pos = atomicAdd(&fill[d], 1);
    csr[pos] = src[e];
  }
}

// ---------------- W1 split + transpose: W1th/W1tl[n][k] = hi/lo(W1[k][n]) ----------------

__global__ __launch_bounds__(256) void w1split_k(const float* __restrict__ W1,
                                                 ushort_t* __restrict__ W1th,
                                                 ushort_t* __restrict__ W1tl) {
  __shared__ ushort_t lh[32 * 65];
  __shared__ ushort_t ll[32 * 65];
  int tid = threadIdx.x;
  int k0 = blockIdx.x * 64;
  int n0 = blockIdx.y * 32;
#pragma unroll
  for (int i = 0; i < 8; i++) {
    int c = tid + 256 * i;
    int kr = c >> 5, nc = c & 31;
    float v = W1[(size_t)(k0 + kr) * F1 + n0 + nc];
    ushort_t h = f2bf(v);
    ushort_t l = f2bf(v - bf2f(h));
    lh[nc * 65 + kr] = h;
    ll[nc * 65 + kr] = l;
  }
  __syncthreads();
#pragma unroll
  for (int i = 0; i < 2; i++) {
    int c = tid + 256 * i;
    int buf = c >> 8;
    int cc = c & 255;
    int nr = cc >> 3, kc = cc & 7;
    const ushort_t* l = buf ? ll : lh;
    uint4 u;
    u.x = (uint_t)l[nr * 65 + kc * 8 + 0] | ((uint_t)l[nr * 65 + kc * 8 + 1] << 16);
    u.y = (uint_t)l[nr * 65 + kc * 8 + 2] | ((uint_t)l[nr * 65 + kc * 8 + 3] << 16);
    u.z = (uint_t)l[nr * 65 + kc * 8 + 4] | ((uint_t)l[nr * 65 + kc * 8 + 5] << 16);
    u.w = (uint_t)l[nr * 65 + kc * 8 + 6] | ((uint_t)l[nr * 65 + kc * 8 + 7] << 16);
    ushort_t* dst = (buf ? W1tl : W1th) + (size_t)(n0 + nr) * N_NODES + k0 + kc * 8;
    *(uint4*)dst = u;
  }
}

// ---------------- GEMM1: streaming, 4 blocks/CU, K-phase ROTATION ----------------
// Identical to round-11 kernel except each block walks its 32 K-steps starting
// at phase s0 = (5*by + 4*bx) mod 32, wrapping. DRAM-channel decorrelation:
// x rows are 32KB (address-aligned comb); rotation spreads the chip-wide
// instantaneous address set across all k-phases -> all HBM channels busy.
// Accumulation order change is within tolerance and deterministic.

#define OAH 0
#define OAL 4096
#define OBB(b) (8192 + (b) * 16384)  // +0: BH (128x64B), +8192: BL

#define SCHED0 __builtin_amdgcn_sched_barrier(0)
#define WAITVM(N)  do { asm volatile("s_waitcnt vmcnt(" #N ")" ::: "memory"); SCHED0; } while (0)
#define WAITVML(N) do { asm volatile("s_waitcnt vmcnt(" #N ") lgkmcnt(0)" ::: "memory"); SCHED0; } while (0)

__global__ __launch_bounds__(256, 4) void gemm1_mfma_k(const float* __restrict__ x,
                                                       const ushort_t* __restrict__ W1th,
                                                       const ushort_t* __restrict__ W1tl,
                                                       float* __restrict__ part, int kspan) {
  __shared__ __align__(16) char lds[40960];
  int tid = threadIdx.x;
  int wave = tid >> 6, lane = tid & 63;
  int wr = wave >> 1, wc = wave & 1;
  int lrow = lane & 15, kgrp = lane >> 4;
  int m_blk = blockIdx.y * 64;
  int kbase = blockIdx.x * kspan;
  int ktiles = kspan >> 5;  // BK=32

  // per-block K-phase rotation (the one change vs round 11)
  int s0 = (5 * blockIdx.y + 4 * blockIdx.x) & (ktiles - 1);

  // B gload constants: wave q covers rows q*32..q*32+31 of BOTH H and L halves.
  // dest lane l -> row q*32+i*16+(l>>2), slot l&3; source k-block = slot^(row&3).
  int bq = wave;
  int b_row = bq * 32 + (lane >> 2);                  // + i*16
  int b_kel = ((lane & 3) ^ ((lane >> 2) & 3)) << 3;  // pre-swizzled k elems

  ffrag acc[2][4];
#pragma unroll
  for (int mi = 0; mi < 2; mi++)
#pragma unroll
    for (int ni = 0; ni < 4; ni++) acc[mi][ni] = (ffrag)(0.0f);

  float4 av[2];  // A staging (8 VGPR)

#define LOADA(K0)                                                                    \
  {                                                                                  \
    _Pragma("unroll") for (int i = 0; i < 2; i++) {                                  \
      int c = tid + 256 * i;                                                         \
      int row = c >> 3, c4 = c & 7;                                                  \
      av[i] = *(const float4*)&x[(size_t)(m_blk + row) * N_NODES + (K0) + 4 * c4];   \
    }                                                                                \
  }

#define ISSUE_B(K0, BSEL)                                                            \
  {                                                                                  \
    _Pragma("unroll") for (int i = 0; i < 2; i++) {                                  \
      const ushort_t* gh = W1th + (size_t)(b_row + i * 16) * N_NODES + (K0) + b_kel; \
      gload16(gh, lds + OBB(BSEL) + bq * 2048 + i * 1024);                           \
      const ushort_t* gl = W1tl + (size_t)(b_row + i * 16) * N_NODES + (K0) + b_kel; \
      gload16(gl, lds + OBB(BSEL) + 8192 + bq * 2048 + i * 1024);                    \
    }                                                                                \
  }

#define STOREA()                                                                     \
  {                                                                                  \
    _Pragma("unroll") for (int i = 0; i < 2; i++) {                                  \
      int c = tid + 256 * i;                                                         \
      int row = c >> 3, c4 = c & 7;                                                  \
      float f0 = av[i].x, f1 = av[i].y, f2 = av[i].z, f3 = av[i].w;                  \
      ushort_t h0 = f2bf(f0), h1 = f2bf(f1), h2 = f2bf(f2), h3 = f2bf(f3);           \
      ushort_t l0 = f2bf(f0 - bf2f(h0)), l1 = f2bf(f1 - bf2f(h1));                   \
      ushort_t l2 = f2bf(f2 - bf2f(h2)), l3 = f2bf(f3 - bf2f(h3));                   \
      uint2 hp, lp;                                                                  \
      hp.x = (uint_t)h0 | ((uint_t)h1 << 16); hp.y = (uint_t)h2 | ((uint_t)h3 << 16);\
      lp.x = (uint_t)l0 | ((uint_t)l1 << 16); lp.y = (uint_t)l2 | ((uint_t)l3 << 16);\
      uint_t off = row * 64 + ((c4 * 8) ^ ((row & 3) << 4));                         \
      *(uint2*)(lds + OAH + off) = hp;                                               \
      *(uint2*)(lds + OAL + off) = lp;                                               \
    }                                                                                \
  }

#define COMPUTE(BSEL)                                                                \
  {                                                                                  \
    bfrag bh[4], bl[4];                                                              \
    _Pragma("unroll") for (int ni = 0; ni < 4; ni++) {                               \
      int brow = wc * 64 + ni * 16 + lrow;                                           \
      uint_t boff = brow * 64 + ((kgrp * 16) ^ ((brow & 3) << 4));                   \
      bh[ni] = *(const bfrag*)(lds + OBB(BSEL) + boff);                              \
      bl[ni] = *(const bfrag*)(lds + OBB(BSEL) + 8192 + boff);                       \
    }                                                                                \
    _Pragma("unroll") for (int mi = 0; mi < 2; mi++) {                               \
      int arow = wr * 32 + mi * 16 + lrow;                                           \
      uint_t aoff = arow * 64 + ((kgrp * 16) ^ ((arow & 3) << 4));                   \
      bfrag ah = *(const bfrag*)(lds + OAH + aoff);                                  \
      bfrag al = *(const bfrag*)(lds + OAL + aoff);                                  \
      _Pragma("unroll") for (int ni = 0; ni < 4; ni++) {                             \
        acc[mi][ni] = __builtin_amdgcn_mfma_f32_16x16x32_bf16(ah, bh[ni], acc[mi][ni], 0, 0, 0); \
        acc[mi][ni] = __builtin_amdgcn_mfma_f32_16x16x32_bf16(ah, bl[ni], acc[mi][ni], 0, 0, 0); \
        acc[mi][ni] = __builtin_amdgcn_mfma_f32_16x16x32_bf16(al, bh[ni], acc[mi][ni], 0, 0, 0); \
      }                                                                              \
    }                                                                                \
  }

  // -------- prologue: stage step s0 --------
  LOADA(kbase + (s0 << 5));
  ISSUE_B(kbase + (s0 << 5), 0);
  WAITVM(4);       // av landed; 4 B gloads may stay in flight
  STOREA();
  WAITVML(0);      // B0 in LDS + A ds_writes visible
  __builtin_amdgcn_s_barrier();
  SCHED0;

  int sp = s0;
  for (int s = 0; s < ktiles; ++s) {
    int more = (s + 1 < ktiles);
    int spn = sp + 1; if (spn == ktiles) spn = 0;
    if (more) {
      int k0n = kbase + (spn << 5);
      LOADA(k0n);                 // av (oldest 2 vm)
      SCHED0;
      ISSUE_B(k0n, (s + 1) & 1);  // 4 vm
      SCHED0;
    }
    __builtin_amdgcn_s_setprio(1);
    COMPUTE(s & 1);
    __builtin_amdgcn_s_setprio(0);
    __builtin_amdgcn_s_barrier();  // all waves done reading Abuf + B(s)
    SCHED0;
    if (more) {
      WAITVM(4);   // av landed (B(s+1) stays in flight)
      STOREA();
      WAITVML(0);  // B(s+1) landed + A writes drained
      __builtin_amdgcn_s_barrier();
      SCHED0;
    }
    sp = spn;
  }

  // -------- epilogue: C[row=(lane>>4)*4+r][col=lane&15] per 16x16 frag --------
  float* outp = part + (size_t)blockIdx.x * (N_NODES * F1);
#pragma unroll
  for (int mi = 0; mi < 2; mi++) {
#pragma unroll
    for (int ni = 0; ni < 4; ni++) {
      int col = wc * 64 + ni * 16 + lrow;
#pragma unroll
      for (int r = 0; r < 4; r++) {
        int row = m_blk + wr * 32 + mi * 16 + kgrp * 4 + r;
        outp[(size_t)row * F1 + col] = acc[mi][ni][r];
      }
    }
  }
#undef LOADA
#undef ISSUE_B
#undef STOREA
#undef COMPUTE
}

// in-place safe: each thread reads all S parts at its index, then writes part[0].
__global__ void reduceS_k(const float* __restrict__ part, float* __restrict__ xw1, int S) {
  int i = blockIdx.x * blockDim.x + threadIdx.x;
  float4 a = ((const float4*)part)[i];
  for (int s = 1; s < S; s++) {
    float4 b = ((const float4*)(part + (size_t)s * N_NODES * F1))[i];
    a.x += b.x; a.y += b.y; a.z += b.z; a.w += b.w;
  }
  ((float4*)xw1)[i] = a;
}

// ---------------- aggregation (gather over CSR) + bias + relu ----------------

template <int F>
__global__ void agg_k(const float* __restrict__ xw, const int* __restrict__ csr,
                      const int* __restrict__ rp, const float* __restrict__ dinv,
                      const float* __restrict__ bias, float* __restrict__ hout) {
  int node = blockIdx.x;
  int f = threadIdx.x;  // F threads
  __shared__ int sidx[F];
  __shared__ float sdv[F];
  int beg = rp[node], end = rp[node + 1];
  float acc = 0.f;
  for (int base = beg; base < end; base += F) {
    int n = end - base;
    if (n > F) n = F;
    __syncthreads();
    if (f < n) {
      int s = csr[base + f];
      sidx[f] = s;
      sdv[f] = dinv[s];
    }
    __syncthreads();
    for (int i = 0; i < n; i++) acc += xw[(size_t)sidx[i] * F + f] * sdv[i];
  }
  float dv = dinv[node];
  float v = (acc + xw[(size_t)node * F + f] * dv) * dv + bias[f];
  hout[(size_t)node * F + f] = v > 0.f ? v : 0.f;
}

// ---------------- GEMM2: h1[8192,128] @ W2[128,64] ----------------

__global__ __launch_bounds__(256) void gemm2_k(const float* __restrict__ h1,
                                               const float* __restrict__ W2,
                                               float* __restrict__ xw2) {
  __shared__ float W2s[F1 * F2];
  __shared__ float As[16 * F1];
  int tid = threadIdx.x;
  int r0 = blockIdx.x * 16;
#pragma unroll
  for (int j = 0; j < 8; j++)
    ((float4*)W2s)[tid + 256 * j] = ((const float4*)W2)[tid + 256 * j];
#pragma unroll
  for (int j = 0; j < 2; j++)
    ((float4*)As)[tid + 256 * j] = ((const float4*)(h1 + (size_t)r0 * F1))[tid + 256 * j];
  __syncthreads();
  int r = tid >> 4, c4 = tid & 15;
  float4 acc = make_float4(0.f, 0.f, 0.f, 0.f);
#pragma unroll 8
  for (int k = 0; k < F1; k++) {
    float a = As[r * F1 + k];
    float4 bv = *(float4*)&W2s[k * F2 + 4 * c4];
    acc.x += a * bv.x; acc.y += a * bv.y; acc.z += a * bv.z; acc.w += a * bv.w;
  }
  *(float4*)&xw2[(size_t)(r0 + r) * F2 + 4 * c4] = acc;
}

// ---------------- P tables: P[i][0:86]=h2[i]@Wfc[:64], P[i][86:172]=h2[i]@Wfc[64:] ----------------

__global__ void pboth_k(const float* __restrict__ h2, const float* __restrict__ Wfc,
                        float* __restrict__ P) {
  __shared__ float hs[64 * 16];
  int tid = threadIdx.x;  // 192
  int r0 = blockIdx.x * 16;
  for (int idx = tid; idx < 256; idx += 192) {
    int row = idx >> 4, k4 = idx & 15;
    float4 h = *(const float4*)&h2[(size_t)(r0 + row) * F2 + 4 * k4];
    hs[(4 * k4 + 0) * 16 + row] = h.x;
    hs[(4 * k4 + 1) * 16 + row] = h.y;
    hs[(4 * k4 + 2) * 16 + row] = h.z;
    hs[(4 * k4 + 3) * 16 + row] = h.w;
  }
  __syncthreads();
  if (tid < 172) {
    int half = tid < 86 ? 0 : 1;
    int j = tid - 86 * half;
    const float* wp = Wfc + (size_t)(64 * half) * N_TYPES + j;
    float acc[16];
#pragma unroll
    for (int r = 0; r < 16; r++) acc[r] = 0.f;
    for (int k = 0; k < 64; k++) {
      float w = wp[(size_t)k * N_TYPES];
      const float* hk = &hs[k * 16];
#pragma unroll
      for (int r = 0; r < 16; r++) acc[r] += hk[r] * w;
    }
#pragma unroll
    for (int r = 0; r < 16; r++) P[(size_t)(r0 + r) * 172 + tid] = acc[r];
  }
}

// ---------------- final: out[p][t] = sigmoid(P1[d1[p]][t] + P2[d2[p]][t] + bfc[t]) ----------------

__global__ void final_k(const float* __restrict__ P, const int* __restrict__ d1,
                        const int* __restrict__ d2, const float* __restrict__ bfc,
                        float* __restrict__ out) {
  int gid = blockIdx.x * blockDim.x + threadIdx.x;
  if (gid >= N_PAIRS * 43) return;
  int p = gid / 43;
  int j = gid - p * 43;
  int a = d1[p], b = d2[p];
  float2 v1 = *(const float2*)&P[(size_t)a * 172 + 2 * j];
  float2 v2 = *(const float2*)&P[(size_t)b * 172 + 86 + 2 * j];
  float2 bb = *(const float2*)&bfc[2 * j];
  float z0 = v1.x + v2.x + bb.x;
  float z1 = v1.y + v2.y + bb.y;
  float2 o;
  o.x = 1.0f / (1.0f + expf(-z0));
  o.y = 1.0f / (1.0f + expf(-z1));
  *(float2*)&out[(size_t)p * 86 + 2 * j] = o;
}

// ---------------- launch ----------------

extern "C" void kernel_launch(void* const* d_in, const int* in_sizes, int n_in,
                              void* d_out, int out_size, void* d_ws, size_t ws_size,
                              hipStream_t stream) {
  const float* x   = (const float*)d_in[0];
  const int*   ei  = (const int*)d_in[1];
  const int*   d1  = (const int*)d_in[2];
  const int*   d2  = (const int*)d_in[3];
  const float* W1  = (const float*)d_in[4];
  const float* b1  = (const float*)d_in[5];
  const float* W2  = (const float*)d_in[6];
  const float* b2  = (const float*)d_in[7];
  const float* Wfc = (const float*)d_in[8];
  const float* bfc = (const float*)d_in[9];
  float* out = (float*)d_out;

  const int* esrc = ei;
  const int* edst = ei + N_EDGES;

  char* w = (char*)d_ws;
  size_t off = 0;
  auto alloc = [&](size_t bytes) -> char* {
    char* p = w + off;
    off += (bytes + 255) & ~(size_t)255;
    return p;
  };
  int*      cnt  = (int*)alloc((size_t)N_NODES * 4);
  float*    dinv = (float*)alloc((size_t)N_NODES * 4);
  int*      rp   = (int*)alloc((size_t)(N_NODES + 1) * 4);
  int*      fill = (int*)alloc((size_t)N_NODES * 4);
  int*      csr  = (int*)alloc((size_t)N_EDGES * 4);
  ushort_t* W1th = (ushort_t*)alloc((size_t)N_NODES * F1 * 2);
  ushort_t* W1tl = (ushort_t*)alloc((size_t)N_NODES * F1 * 2);
  float*    h1   = (float*)alloc((size_t)N_NODES * F1 * 4);
  float*    xw2  = (float*)alloc((size_t)N_NODES * F2 * 4);
  float*    h2   = (float*)alloc((size_t)N_NODES * F2 * 4);
  float*    P    = (float*)alloc((size_t)N_NODES * 172 * 4);

  size_t partBytes = (size_t)N_NODES * F1 * 4;  // 4MB per split
  int S = 8;
  while (S > 1 && off + (size_t)S * partBytes > ws_size) S >>= 1;
  float* part = (float*)alloc((size_t)S * partBytes);
  float* xw1 = part;  // alias; reduceS_k is index-aligned in-place safe
  if (off > ws_size) return;

  zero_k<<<N_NODES / 256, 256, 0, stream>>>(cnt);
  count_deg_k<<<N_EDGES / 256, 256, 0, stream>>>(edst, cnt);
  scan_k<<<1, 1024, 0, stream>>>(cnt, rp, fill, dinv);
  scatter_k<<<N_EDGES / 256, 256, 0, stream>>>(esrc, edst, fill, csr);

  w1split_k<<<dim3(N_NODES / 64, F1 / 32), 256, 0, stream>>>(W1, W1th, W1tl);
  // grid (S, M-blocks): wgid%S == K-slice -> per-XCD B-slice L2 locality
  gemm1_mfma_k<<<dim3(S, N_NODES / 64), 256, 0, stream>>>(x, W1th, W1tl, part, N_NODES / S);
  if (S > 1)
    reduceS_k<<<(N_NODES * F1 / 4) / 256, 256, 0, stream>>>(part, xw1, S);
  agg_k<F1><<<N_NODES, F1, 0, stream>>>(xw1, csr, rp, dinv, b1, h1);

  gemm2_k<<<N_NODES / 16, 256, 0, stream>>>(h1, W2, xw2);
  agg_k<F2><<<N_NODES, F2, 0, stream>>>(xw2, csr, rp, dinv, b2, h2);

  pboth_k<<<N_NODES / 16, 192, 0, stream>>>(h2, Wfc, P);
  final_k<<<(N_PAIRS * 43 + 255) / 256, 256, 0, stream>>>(P, d1, d2, bfc, out);
}